// Round 6
// baseline (61.517 us; speedup 1.0000x reference)
//
#include <hip/hip_runtime.h>
#include <hip/hip_bf16.h>

#define VOCAB 128
#define HIDDEN 128

typedef float f32x4 __attribute__((ext_vector_type(4)));

// Block o computes column o of both tables:
//   T1[v][o] = sum_h emb[v][h] * W[o][h]       + b[o]
//   T2[v][o] = sum_h emb[v][h] * W[o][128+h]
// emb staged in LDS (coalesced), lane = v; W row o / b[o] wave-uniform.
__global__ __launch_bounds__(128) void precompute_tables(
        const float* __restrict__ emb,
        const float* __restrict__ W,
        const float* __restrict__ b,
        float* __restrict__ T1,
        float* __restrict__ T2) {
    __shared__ float es[VOCAB * (HIDDEN + 1)];
    int t = threadIdx.x;
    int o = blockIdx.x;

    for (int i = 0; i < (VOCAB * HIDDEN) / (128 * 4); ++i) {
        int f = (i * 128 + t) * 4;
        f32x4 val = *reinterpret_cast<const f32x4*>(emb + f);
        int v = f >> 7;
        int h = f & 127;
        float* d = es + v * (HIDDEN + 1) + h;
        d[0] = val.x; d[1] = val.y; d[2] = val.z; d[3] = val.w;
    }
    __syncthreads();

    int v = t;
    const float* wr = W + o * (2 * HIDDEN);
    const float* er = es + v * (HIDDEN + 1);
    float s1 = 0.f, s2 = 0.f;
#pragma unroll 16
    for (int h = 0; h < HIDDEN; ++h) {
        float ev = er[h];
        s1 += ev * wr[h];
        s2 += ev * wr[HIDDEN + h];
    }
    T1[v * HIDDEN + o] = s1 + b[o];
    T2[v * HIDDEN + o] = s2;
}

// 32 lanes per edge, one float4 per lane; grid fixed at 2048x256 so the
// edge stride is 16384 and q is loop-invariant. Per-thread trip count is
// precomputed; unroll 4 puts 4 independent read-chains + nt stores in
// flight per wave.
#define EDGE_GRID 2048
#define EDGE_BLOCK 256
#define EDGE_ES ((EDGE_GRID * EDGE_BLOCK) / 32)   // 16384

__global__ __launch_bounds__(EDGE_BLOCK) void edge_gather_add(
        const int* __restrict__ z,
        const int* __restrict__ src,
        const int* __restrict__ dst,
        const float* __restrict__ T1,
        const float* __restrict__ T2,
        float* __restrict__ out,
        int E) {
    int tid = blockIdx.x * EDGE_BLOCK + threadIdx.x;
    int e   = tid >> 5;
    int q4  = (tid & 31) << 2;                 // invariant float offset
    const float* t1 = T1 + q4;
    const float* t2 = T2 + q4;
    float* op = out + (size_t)e * HIDDEN + q4;
    int nIter = (e < E) ? ((E - 1 - e) / EDGE_ES + 1) : 0;
#pragma unroll 4
    for (int k = 0; k < nIter; ++k) {
        int ee = e + k * EDGE_ES;
        int s  = src[ee];
        int d  = dst[ee];
        int zs = z[s];
        int zd = z[d];
        f32x4 a = *reinterpret_cast<const f32x4*>(t1 + zs * HIDDEN);
        f32x4 c = *reinterpret_cast<const f32x4*>(t2 + zd * HIDDEN);
        f32x4 r = a + c;
        __builtin_nontemporal_store(r,
            reinterpret_cast<f32x4*>(op + (size_t)k * EDGE_ES * HIDDEN));
    }
}

extern "C" void kernel_launch(void* const* d_in, const int* in_sizes, int n_in,
                              void* d_out, int out_size, void* d_ws, size_t ws_size,
                              hipStream_t stream) {
    const int*   z    = (const int*)d_in[0];          // [N_NODES]
    const int*   ei   = (const int*)d_in[1];          // [2, E] row-major
    const float* emb  = (const float*)d_in[2];        // [128, 128]
    const float* W    = (const float*)d_in[3];        // [128, 256]
    const float* b    = (const float*)d_in[4];        // [128]
    float*       out  = (float*)d_out;                // [E, 128]

    int E = in_sizes[1] / 2;
    const int* src = ei;
    const int* dst = ei + E;

    float* T1 = (float*)d_ws;                         // 64 KB
    float* T2 = T1 + VOCAB * HIDDEN;                  // 64 KB

    precompute_tables<<<VOCAB, 128, 0, stream>>>(emb, W, b, T1, T2);

    edge_gather_add<<<EDGE_GRID, EDGE_BLOCK, 0, stream>>>(z, src, dst, T1, T2, out, E);
}

// Round 7
// 58.965 us; speedup vs baseline: 1.0433x; 1.0433x over previous
//
#include <hip/hip_runtime.h>
#include <hip/hip_bf16.h>

#define VOCAB 128
#define HIDDEN 128

typedef float f32x4 __attribute__((ext_vector_type(4)));

// Block o computes column o of both tables:
//   T1[v][o] = sum_h emb[v][h] * W[o][h]       + b[o]
//   T2[v][o] = sum_h emb[v][h] * W[o][128+h]
// emb staged in LDS (coalesced), lane = v; W row o / b[o] wave-uniform.
__global__ __launch_bounds__(128) void precompute_tables(
        const float* __restrict__ emb,
        const float* __restrict__ W,
        const float* __restrict__ b,
        float* __restrict__ T1,
        float* __restrict__ T2) {
    __shared__ float es[VOCAB * (HIDDEN + 1)];
    int t = threadIdx.x;
    int o = blockIdx.x;

    for (int i = 0; i < (VOCAB * HIDDEN) / (128 * 4); ++i) {
        int f = (i * 128 + t) * 4;
        f32x4 val = *reinterpret_cast<const f32x4*>(emb + f);
        int v = f >> 7;
        int h = f & 127;
        float* d = es + v * (HIDDEN + 1) + h;
        d[0] = val.x; d[1] = val.y; d[2] = val.z; d[3] = val.w;
    }
    __syncthreads();

    int v = t;
    const float* wr = W + o * (2 * HIDDEN);
    const float* er = es + v * (HIDDEN + 1);
    float s1 = 0.f, s2 = 0.f;
#pragma unroll 16
    for (int h = 0; h < HIDDEN; ++h) {
        float ev = er[h];
        s1 += ev * wr[h];
        s2 += ev * wr[HIDDEN + h];
    }
    T1[v * HIDDEN + o] = s1 + b[o];
    T2[v * HIDDEN + o] = s2;
}

// Edge kernel: tables live in 128 KB LDS (immune to L2 eviction by the
// 256 MB output stream), stores are REGULAR float4 (L2 write-back path,
// which the fill kernel shows sustains ~7 TB/s). 32 lanes per edge, one
// float4 per lane -> each wave store is 1024 B fully contiguous.
#define EDGE_BLOCK 1024
#define EDGE_GRID  256
#define TBL_FLOATS (2 * VOCAB * HIDDEN)   // 32768 floats = 128 KB

__global__ __launch_bounds__(EDGE_BLOCK) void edge_gather_add(
        const int* __restrict__ z,
        const int* __restrict__ src,
        const int* __restrict__ dst,
        const float* __restrict__ Tg,   // T1 | T2 contiguous, 32768 floats
        float* __restrict__ out,
        int E) {
    extern __shared__ float lds[];      // [0..16383] = T1, [16384..] = T2
    int t = threadIdx.x;

    // Stage both tables: 8192 float4, 1024 threads, 8 iterations.
#pragma unroll
    for (int i = 0; i < TBL_FLOATS / (EDGE_BLOCK * 4); ++i) {
        int f = (i * EDGE_BLOCK + t) * 4;
        *reinterpret_cast<f32x4*>(lds + f) =
            *reinterpret_cast<const f32x4*>(Tg + f);
    }
    __syncthreads();

    const float* lT2 = lds + VOCAB * HIDDEN;
    int total = E * 32;
    int stride = gridDim.x * EDGE_BLOCK;
    for (int idx = blockIdx.x * EDGE_BLOCK + t; idx < total; idx += stride) {
        int e = idx >> 5;
        int q4 = (idx & 31) << 2;
        int zs = z[src[e]];
        int zd = z[dst[e]];
        f32x4 a = *reinterpret_cast<const f32x4*>(lds + zs * HIDDEN + q4);
        f32x4 c = *reinterpret_cast<const f32x4*>(lT2 + zd * HIDDEN + q4);
        f32x4 r = a + c;
        *reinterpret_cast<f32x4*>(out + (size_t)e * HIDDEN + q4) = r;
    }
}

extern "C" void kernel_launch(void* const* d_in, const int* in_sizes, int n_in,
                              void* d_out, int out_size, void* d_ws, size_t ws_size,
                              hipStream_t stream) {
    const int*   z    = (const int*)d_in[0];          // [N_NODES]
    const int*   ei   = (const int*)d_in[1];          // [2, E] row-major
    const float* emb  = (const float*)d_in[2];        // [128, 128]
    const float* W    = (const float*)d_in[3];        // [128, 256]
    const float* b    = (const float*)d_in[4];        // [128]
    float*       out  = (float*)d_out;                // [E, 128]

    int E = in_sizes[1] / 2;
    const int* src = ei;
    const int* dst = ei + E;

    float* T1 = (float*)d_ws;                         // 64 KB
    float* T2 = T1 + VOCAB * HIDDEN;                  // 64 KB (contiguous)

    precompute_tables<<<VOCAB, 128, 0, stream>>>(emb, W, b, T1, T2);

    static bool attr_set = false;
    if (!attr_set) {
        hipFuncSetAttribute((const void*)edge_gather_add,
                            hipFuncAttributeMaxDynamicSharedMemorySize,
                            TBL_FLOATS * 4);
        attr_set = true;
    }
    edge_gather_add<<<EDGE_GRID, EDGE_BLOCK, TBL_FLOATS * 4, stream>>>(
        z, src, dst, T1, out, E);
}

// Round 8
// 50.741 us; speedup vs baseline: 1.2124x; 1.1621x over previous
//
#include <hip/hip_runtime.h>
#include <hip/hip_bf16.h>

#define VOCAB 128
#define HIDDEN 128

typedef float f32x4 __attribute__((ext_vector_type(4)));

// Block o computes column o of both tables; threads 0-127 (waves 0,1) do
//   T1[v][o] = sum_h emb[v][h]*W[o][h] + b[o],
// threads 128-255 (waves 2,3) do
//   T2[v][o] = sum_h emb[v][h]*W[o][128+h].
// 'which' is wave-uniform -> W row pointer stays scalar. 128-MAC dot each.
__global__ __launch_bounds__(256) void precompute_tables(
        const float* __restrict__ emb,
        const float* __restrict__ W,
        const float* __restrict__ b,
        float* __restrict__ T1,
        float* __restrict__ T2) {
    __shared__ float es[VOCAB * (HIDDEN + 1)];
    int t = threadIdx.x;
    int o = blockIdx.x;

    // Stage emb: 16384 floats, 256 threads x f32x4 x 16 iters, coalesced.
    for (int i = 0; i < (VOCAB * HIDDEN) / (256 * 4); ++i) {
        int f = (i * 256 + t) * 4;
        f32x4 val = *reinterpret_cast<const f32x4*>(emb + f);
        int v = f >> 7;
        int h = f & 127;
        float* d = es + v * (HIDDEN + 1) + h;   // rows of 128 stay intact
        d[0] = val.x; d[1] = val.y; d[2] = val.z; d[3] = val.w;
    }
    __syncthreads();

    int v = t & 127;
    int which = t >> 7;                          // wave-uniform
    const float* wr = W + o * (2 * HIDDEN) + which * HIDDEN;
    const float* er = es + v * (HIDDEN + 1);
    float s = 0.f;
#pragma unroll 16
    for (int h = 0; h < HIDDEN; ++h)
        s += er[h] * wr[h];
    if (which == 0) T1[v * HIDDEN + o] = s + b[o];
    else            T2[v * HIDDEN + o] = s;
}

// Edge kernel (R4 structure — best measured): 32 lanes per edge, one
// float4 per lane, nt stores (1024 B fully contiguous per wave store).
// Tables read through L1/L2 (proven non-limiting in R5/R6).
// Grid 1024 x 256 = 16 waves/CU: fill hits 7 TB/s at ~3 waves/CU, so
// 32 waves was pure oversubscription.
__global__ __launch_bounds__(256) void edge_gather_add(
        const int* __restrict__ z,
        const int* __restrict__ src,
        const int* __restrict__ dst,
        const float* __restrict__ T1,
        const float* __restrict__ T2,
        float* __restrict__ out,
        int E) {
    int total = E * 32;
    int stride = gridDim.x * blockDim.x;
    for (int idx = blockIdx.x * blockDim.x + threadIdx.x; idx < total; idx += stride) {
        int e = idx >> 5;
        int q = idx & 31;
        int zs = z[src[e]];
        int zd = z[dst[e]];
        f32x4 a = *reinterpret_cast<const f32x4*>(T1 + zs * HIDDEN + q * 4);
        f32x4 c = *reinterpret_cast<const f32x4*>(T2 + zd * HIDDEN + q * 4);
        f32x4 r = a + c;
        __builtin_nontemporal_store(r, reinterpret_cast<f32x4*>(out + (size_t)e * HIDDEN + q * 4));
    }
}

extern "C" void kernel_launch(void* const* d_in, const int* in_sizes, int n_in,
                              void* d_out, int out_size, void* d_ws, size_t ws_size,
                              hipStream_t stream) {
    const int*   z    = (const int*)d_in[0];          // [N_NODES]
    const int*   ei   = (const int*)d_in[1];          // [2, E] row-major
    const float* emb  = (const float*)d_in[2];        // [128, 128]
    const float* W    = (const float*)d_in[3];        // [128, 256]
    const float* b    = (const float*)d_in[4];        // [128]
    float*       out  = (float*)d_out;                // [E, 128]

    int E = in_sizes[1] / 2;
    const int* src = ei;
    const int* dst = ei + E;

    float* T1 = (float*)d_ws;                         // 64 KB
    float* T2 = T1 + VOCAB * HIDDEN;                  // 64 KB

    precompute_tables<<<VOCAB, 256, 0, stream>>>(emb, W, b, T1, T2);

    edge_gather_add<<<1024, 256, 0, stream>>>(z, src, dst, T1, T2, out, E);
}